// Round 1
// baseline (2468.148 us; speedup 1.0000x reference)
//
#include <hip/hip_runtime.h>

typedef unsigned short u16;
typedef __attribute__((ext_vector_type(8))) short short8;
typedef __attribute__((ext_vector_type(8))) __bf16 bf16x8;
typedef __attribute__((ext_vector_type(4))) float f32x4;

#define DEV __device__ __forceinline__

// ---------- scalar helpers ----------
DEV u16 f2bf(float f){ unsigned u = __float_as_uint(f); return (u16)((u + 0x7fffu + ((u>>16)&1u)) >> 16); }
DEV float bf2f(u16 h){ return __uint_as_float(((unsigned)h)<<16); }

DEV f32x4 mfma_bf16(short8 a, short8 b, f32x4 c){
  return __builtin_amdgcn_mfma_f32_16x16x32_bf16(
      __builtin_bit_cast(bf16x8, a), __builtin_bit_cast(bf16x8, b), c, 0, 0, 0);
}

DEV void gl2lds16(const u16* g, u16* s){
  __builtin_amdgcn_global_load_lds(
      (__attribute__((address_space(1))) void*)(g),
      (__attribute__((address_space(3))) void*)(s), 16, 0, 0);
}

// problem constants
#define BB 8
#define HH 48
#define WW 192
#define CC 512
#define NTOK (BB*HH*WW)        // 73728

// ---------- weight prep ----------
__global__ void k_permqkv(const float* __restrict__ w, u16* __restrict__ o){
  int i = blockIdx.x*256 + threadIdx.x;          // 1536*512 total
  int n = i >> 9, kk = i & 511;
  int src = 3*(n & 511) + (n >> 9);
  o[i] = f2bf(w[src*512 + kk]);
}
__global__ void k_conv(const float* __restrict__ w, u16* __restrict__ o, int nelem){
  int i = blockIdx.x*256 + threadIdx.x;
  if (i < nelem) o[i] = f2bf(w[i]);
}

// ---------- transpose in: x (B,C,H,W) f32 -> xres (B,H,W,C) f32 ----------
__global__ void k_tin(const float* __restrict__ x, float* __restrict__ xr){
  __shared__ float T[32][33];
  int bh = blockIdx.x / 96, rem = blockIdx.x % 96;
  int c0 = (rem/6)*32, w0 = (rem%6)*32;
  int b = bh / HH, h = bh % HH;
  const float* xp = x + ((size_t)b*CC*HH + h)*WW;     // + c*(HH*WW) + w
  #pragma unroll
  for (int p=0;p<4;p++){
    int idx = p*256 + threadIdx.x;
    int cc = idx >> 5, ww = idx & 31;
    T[cc][ww] = xp[(size_t)(c0+cc)*(HH*WW) + w0 + ww];
  }
  __syncthreads();
  float* xo = xr + (size_t)bh*WW*CC;
  #pragma unroll
  for (int p=0;p<4;p++){
    int idx = p*256 + threadIdx.x;
    int ww = idx >> 5, cc = idx & 31;
    xo[(size_t)(w0+ww)*CC + c0 + cc] = T[cc][ww];
  }
}

// ---------- transpose out: xres (B,H,W,C) f32 -> out (B,C,H,W) f32 ----------
__global__ void k_tout(const float* __restrict__ xr, float* __restrict__ out){
  __shared__ float T[32][33];
  int bh = blockIdx.x / 96, rem = blockIdx.x % 96;
  int c0 = (rem/6)*32, w0 = (rem%6)*32;
  int b = bh / HH, h = bh % HH;
  const float* xi = xr + (size_t)bh*WW*CC;
  #pragma unroll
  for (int p=0;p<4;p++){
    int idx = p*256 + threadIdx.x;
    int ww = idx >> 5, cc = idx & 31;
    T[ww][cc] = xi[(size_t)(w0+ww)*CC + c0 + cc];
  }
  __syncthreads();
  float* op = out + ((size_t)b*CC*HH + h)*WW;
  #pragma unroll
  for (int p=0;p<4;p++){
    int idx = p*256 + threadIdx.x;
    int cc = idx >> 5, ww = idx & 31;
    op[(size_t)(c0+cc)*(HH*WW) + w0 + ww] = T[ww][cc];
  }
}

// ---------- LayerNorm: xres f32 -> y bf16 (wave per token) ----------
__global__ void k_ln(const float* __restrict__ xr, const float* __restrict__ g,
                     const float* __restrict__ bb, u16* __restrict__ y){
  int t = blockIdx.x*4 + (threadIdx.x>>6);
  int lane = threadIdx.x & 63;
  const float* row = xr + (size_t)t*CC + lane*8;
  float v[8];
  *(f32x4*)(v)   = *(const f32x4*)(row);
  *(f32x4*)(v+4) = *(const f32x4*)(row+4);
  float s=0.f, s2=0.f;
  #pragma unroll
  for (int j=0;j<8;j++){ s += v[j]; s2 += v[j]*v[j]; }
  #pragma unroll
  for (int o=32;o;o>>=1){ s += __shfl_xor(s,o); s2 += __shfl_xor(s2,o); }
  float mean = s*(1.f/CC);
  float var  = s2*(1.f/CC) - mean*mean;
  float rs = rsqrtf(var + 1e-5f);
  const float* gp = g + lane*8; const float* bp = bb + lane*8;
  short8 o8;
  #pragma unroll
  for (int j=0;j<8;j++) o8[j] = (short)f2bf((v[j]-mean)*rs*gp[j] + bp[j]);
  *(short8*)(y + (size_t)t*CC + lane*8) = o8;
}

// ---------- GEMM 256x256, BK=64, 8 waves (2x4), deep-pipelined ----------
// T2: XOR-swizzled LDS (inverse-swizzle on global source, swizzled ds_read)
// T3+T4: 4-phase-per-K-tile schedule, counted s_waitcnt vmcnt(4) (never 0 in
//        steady state) with raw s_barrier; loads stay in flight across barriers.
// T5: s_setprio(1) around each 16-MFMA cluster.
// Safety invariants (race-free by construction):
//   - A rows {0-63,128-191} (parts 0,2) are only ds_read in P1; all waves'
//     P1 reads retire at P1/P2 lgkmcnt(0) before BARRIER1 -> t+2 stages of
//     parts 0,2 issue after BARRIER1.
//   - A rows {64-127,192-255} (parts 1,3) ds_read in P3, retired at P3
//     lgkmcnt(0) before BARRIER2 -> t+2 stages of parts 1,3 after BARRIER2.
//   - B of buffer cur fully read by P2 lgkmcnt(0); its regions are only
//     overwritten after the end-of-tile barrier (next tile P1/P2).
//   - vmcnt(4) at tile end retires all of tile t+1's 8 loads (the 4 newest
//     outstanding are tile t+2's A stages). Tail uses vmcnt(0) once.
// epi 0: store bf16 ; epi 1: bf16 + bias + relu ; epi 2: f32 Out += acc (+bias)
template<int EPI>
__global__ __launch_bounds__(512, 2)
void k_gemm256(const u16* __restrict__ A, int lda,
               const u16* __restrict__ Bw, int ldb,
               void* __restrict__ Out, int ldo,
               const float* __restrict__ bias,
               int K, int nbn){
  __shared__ __align__(16) u16 As[2*16384];   // 2 buf x 256 x 64
  __shared__ __align__(16) u16 Bs[2*16384];
  const int tid = threadIdx.x, lane = tid & 63, wv = tid >> 6;
  const int m = lane & 15, quad = lane >> 4;
  const int wr = wv >> 2, wc = wv & 3;        // 2 x 4 wave grid
  const int mb = blockIdx.x / nbn, nb = blockIdx.x % nbn;
  const size_t m0 = (size_t)mb * 256, n0 = (size_t)nb * 256;

  // staging: one call = 8 waves x 8 rows = 64 rows (one part). 4 parts/tile.
  const int srow = wv*8 + (lane >> 3);                  // row within 64-row part... (wv*8 within part-slice)
  const int schk = ((lane & 7) ^ (lane >> 3)) * 8;      // inverse-swizzled source chunk
  const u16* gA = A  + (m0 + srow) * (size_t)lda + schk;
  const u16* gB = Bw + (n0 + srow) * (size_t)ldb + schk;
  const int sdst = wv * 8 * 64;                         // wave-uniform LDS dest within part
  const int NT = K >> 6;

#define STG_A(bufi, tt, p) gl2lds16(gA + (size_t)(p)*64*lda + (size_t)(tt)*64, \
                                    As + (bufi)*16384 + (p)*4096 + sdst)
#define STG_B(bufi, tt, p) gl2lds16(gB + (size_t)(p)*64*ldb + (size_t)(tt)*64, \
                                    Bs + (bufi)*16384 + (p)*4096 + sdst)
#define WAIT_LGKM0 asm volatile("s_waitcnt lgkmcnt(0)" ::: "memory")
#define WAIT_VM4   asm volatile("s_waitcnt vmcnt(4)" ::: "memory")
#define WAIT_VM0   asm volatile("s_waitcnt vmcnt(0)" ::: "memory")
#define SCHED0 __builtin_amdgcn_sched_barrier(0)
#define BAR    __builtin_amdgcn_s_barrier()
#define PRIO1  __builtin_amdgcn_s_setprio(1)
#define PRIO0  __builtin_amdgcn_s_setprio(0)

  // ---- prologue: tile0 fully, tile1 A-parts; leave tile1's A in flight ----
  STG_A(0,0,0); STG_A(0,0,1); STG_A(0,0,2); STG_A(0,0,3);
  STG_B(0,0,0); STG_B(0,0,1); STG_B(0,0,2); STG_B(0,0,3);
  STG_A(1,1,0); STG_A(1,1,2); STG_A(1,1,1); STG_A(1,1,3);

  f32x4 acc[8][4];
  #pragma unroll
  for (int i=0;i<8;i++)
    #pragma unroll
    for (int j=0;j<4;j++) acc[i][j] = (f32x4){0.f,0.f,0.f,0.f};

  const int off0 = ( quad      ^ (m & 7)) * 8;          // k-slice 0
  const int off1 = ((quad + 4) ^ (m & 7)) * 8;          // k-slice 1

  WAIT_VM4;   // tile0's 8 loads retired; tile1's 4 A-loads remain in flight
  BAR;

  for (int t = 0; t < NT; ++t){
    const int buf = t & 1, obuf = buf ^ 1;
    const u16* aB = As + buf*16384 + (wr*128 + m)*64;
    const u16* bB = Bs + buf*16384 + (wc*64  + m)*64;
    short8 av[4][2], bv[4][2];

    // ---- P1: read A(i0-3)+B(j0-1); stage t+1 B0,B1; MFMA (lo,lo) ----
    #pragma unroll
    for (int i=0;i<4;i++){
      av[i][0] = *(const short8*)(aB + i*1024 + off0);
      av[i][1] = *(const short8*)(aB + i*1024 + off1);
    }
    #pragma unroll
    for (int j=0;j<2;j++){
      bv[j][0] = *(const short8*)(bB + j*1024 + off0);
      bv[j][1] = *(const short8*)(bB + j*1024 + off1);
    }
    if (t + 1 < NT){ STG_B(obuf, t+1, 0); STG_B(obuf, t+1, 1); }
    WAIT_LGKM0; SCHED0;
    PRIO1;
    #pragma unroll
    for (int i=0;i<4;i++)
      #pragma unroll
      for (int j=0;j<2;j++){
        acc[i][j] = mfma_bf16(av[i][0], bv[j][0], acc[i][j]);
        acc[i][j] = mfma_bf16(av[i][1], bv[j][1], acc[i][j]);
      }
    PRIO0;

    // ---- P2: read B(j2-3); stage t+1 B2,B3; MFMA (lo,hi); BARRIER1 ----
    #pragma unroll
    for (int j=0;j<2;j++){
      bv[2+j][0] = *(const short8*)(bB + (2+j)*1024 + off0);
      bv[2+j][1] = *(const short8*)(bB + (2+j)*1024 + off1);
    }
    if (t + 1 < NT){ STG_B(obuf, t+1, 2); STG_B(obuf, t+1, 3); }
    WAIT_LGKM0; SCHED0;
    PRIO1;
    #pragma unroll
    for (int i=0;i<4;i++)
      #pragma unroll
      for (int j=0;j<2;j++){
        acc[i][2+j] = mfma_bf16(av[i][0], bv[2+j][0], acc[i][2+j]);
        acc[i][2+j] = mfma_bf16(av[i][1], bv[2+j][1], acc[i][2+j]);
      }
    PRIO0;
    BAR;   // all waves' A(i0-3) + B reads retired -> A parts 0,2 free

    // ---- P3: read A(i4-7); stage t+2 A0,A2; MFMA (hi,hi); BARRIER2 ----
    #pragma unroll
    for (int i=0;i<4;i++){
      av[i][0] = *(const short8*)(aB + (i+4)*1024 + off0);
      av[i][1] = *(const short8*)(aB + (i+4)*1024 + off1);
    }
    if (t + 2 < NT){ STG_A(buf, t+2, 0); STG_A(buf, t+2, 2); }
    WAIT_LGKM0; SCHED0;
    PRIO1;
    #pragma unroll
    for (int i=0;i<4;i++)
      #pragma unroll
      for (int j=0;j<2;j++){
        acc[4+i][2+j] = mfma_bf16(av[i][0], bv[2+j][0], acc[4+i][2+j]);
        acc[4+i][2+j] = mfma_bf16(av[i][1], bv[2+j][1], acc[4+i][2+j]);
      }
    PRIO0;
    BAR;   // all waves' A(i4-7) reads retired -> A parts 1,3 free

    // ---- P4: stage t+2 A1,A3; MFMA (hi,lo); counted vmcnt; barrier ----
    if (t + 2 < NT){ STG_A(buf, t+2, 1); STG_A(buf, t+2, 3); }
    PRIO1;
    #pragma unroll
    for (int i=0;i<4;i++)
      #pragma unroll
      for (int j=0;j<2;j++){
        acc[4+i][j] = mfma_bf16(av[i][0], bv[j][0], acc[4+i][j]);
        acc[4+i][j] = mfma_bf16(av[i][1], bv[j][1], acc[4+i][j]);
      }
    PRIO0;
    if (t + 2 < NT)      { WAIT_VM4; }
    else if (t + 1 < NT) { WAIT_VM0; }
    if (t + 1 < NT) BAR;
  }

#undef STG_A
#undef STG_B

  // ---- epilogue ----
  if (EPI == 2){
    float* O = (float*)Out + (m0 + wr*128 + quad*4)*(size_t)ldo + n0 + wc*64 + m;
    #pragma unroll
    for (int j=0;j<4;j++){
      float bvv = bias ? bias[n0 + wc*64 + j*16 + m] : 0.f;
      #pragma unroll
      for (int i=0;i<8;i++)
        #pragma unroll
        for (int r=0;r<4;r++)
          O[(size_t)(i*16+r)*ldo + j*16] += acc[i][j][r] + bvv;
    }
  } else {
    u16* O = (u16*)Out + (m0 + wr*128 + quad*4)*(size_t)ldo + n0 + wc*64 + m;
    #pragma unroll
    for (int j=0;j<4;j++){
      float bvv = bias ? bias[n0 + wc*64 + j*16 + m] : 0.f;
      #pragma unroll
      for (int i=0;i<8;i++)
        #pragma unroll
        for (int r=0;r<4;r++){
          float v = acc[i][j][r] + bvv;
          if (EPI == 1) v = fmaxf(v, 0.f);
          O[(size_t)(i*16+r)*ldo + j*16] = f2bf(v);
        }
    }
  }
}

// ---------- QK^T: one wave per 16x16 S tile ----------
__global__ void k_qk(const u16* __restrict__ q, const u16* __restrict__ kp, int ldq,
                     float* __restrict__ S, int L, int nt,
                     int SD, int OUTs, int INN, int LST, float scale){
  int blk = blockIdx.x;
  int s = blk / (nt*nt), tl = blk % (nt*nt);
  int ti = tl / nt, tj = tl % nt;
  int lane = threadIdx.x, m = lane & 15, quad = lane >> 4;
  size_t tokbase = (size_t)(s/SD)*OUTs + (size_t)(s%SD)*INN;
  const u16* qr = q  + (tokbase + (size_t)(ti*16+m)*LST)*ldq + quad*8;
  const u16* kr = kp + (tokbase + (size_t)(tj*16+m)*LST)*ldq + quad*8;
  f32x4 acc = (f32x4){0.f,0.f,0.f,0.f};
  #pragma unroll
  for (int kk=0; kk<CC; kk+=32)
    acc = mfma_bf16(*(const short8*)(qr+kk), *(const short8*)(kr+kk), acc);
  float* Sp = S + (size_t)s*L*L + (size_t)(ti*16 + quad*4)*L + tj*16 + m;
  #pragma unroll
  for (int r=0;r<4;r++) Sp[(size_t)r*L] = acc[r]*scale;
}

// ---------- softmax rows (wave per row), write bf16 P padded to Lp ----------
__global__ void k_softmax(const float* __restrict__ S, u16* __restrict__ P, int L, int Lp){
  int row = blockIdx.x*4 + (threadIdx.x>>6);
  int lane = threadIdx.x & 63;
  const float* sr = S + (size_t)row*L;
  float v0 = (lane      < L) ? sr[lane]      : -3.0e38f;
  float v1 = (lane+64   < L) ? sr[lane+64]   : -3.0e38f;
  float v2 = (lane+128  < L) ? sr[lane+128]  : -3.0e38f;
  float mx = fmaxf(v0, fmaxf(v1, v2));
  #pragma unroll
  for (int o=32;o;o>>=1) mx = fmaxf(mx, __shfl_xor(mx, o));
  float e0 = (lane      < L) ? __expf(v0-mx) : 0.f;
  float e1 = (lane+64   < L) ? __expf(v1-mx) : 0.f;
  float e2 = (lane+128  < L) ? __expf(v2-mx) : 0.f;
  float sm = e0+e1+e2;
  #pragma unroll
  for (int o=32;o;o>>=1) sm += __shfl_xor(sm, o);
  float inv = 1.f/sm;
  u16* pr = P + (size_t)row*Lp;
  if (lane      < Lp) pr[lane]      = f2bf(e0*inv);
  if (lane+64   < Lp) pr[lane+64]   = f2bf(e1*inv);
  if (lane+128  < Lp) pr[lane+128]  = f2bf(e2*inv);
}

// ---------- V transpose per sequence: v rows (l,c) -> vt[s][c][l], zero-pad l to Lp ----------
__global__ void k_vt(const u16* __restrict__ v, int ldv, u16* __restrict__ vt,
                     int L, int Lp, int SD, int OUTs, int INN, int LST){
  __shared__ float T[32*193];
  int s = blockIdx.x >> 4;
  int c0 = (blockIdx.x & 15)*32;
  size_t tokbase = (size_t)(s/SD)*OUTs + (size_t)(s%SD)*INN;
  int pad = Lp + 1;
  for (int idx = threadIdx.x; idx < L*32; idx += 256){
    int l = idx >> 5, cc = idx & 31;
    T[cc*pad + l] = bf2f(v[(tokbase + (size_t)l*LST)*ldv + c0 + cc]);
  }
  __syncthreads();
  u16* vo = vt + ((size_t)s*CC + c0)*Lp;
  for (int idx = threadIdx.x; idx < 32*Lp; idx += 256){
    int cc = idx / Lp, l = idx - cc*Lp;
    vo[idx] = (l < L) ? f2bf(T[cc*pad + l]) : (u16)0;
  }
}

// ---------- PV v2: block (256 thr) per (seq, column-group) with LDS staging ----------
template<int L, int Lp, int NTQ, int NCJ>
__global__ __launch_bounds__(256)
void k_pv2(const u16* __restrict__ P, const u16* __restrict__ vt, u16* __restrict__ ctx,
           int SD, int OUTs, int INN, int LST){
  constexpr int G   = 32 / NCJ;          // blocks per sequence
  constexpr int LPP = Lp + 8;            // padded P row stride (u16)
  constexpr int CW  = NCJ * 16;          // ctx columns per block
  constexpr int CJW = NCJ / 4;           // cj tiles per wave
  constexpr int NKS = Lp / 32;           // K steps per MFMA chain
  constexpr int SHW = (L*LPP > L*CW) ? L*LPP : L*CW;
  __shared__ __align__(16) u16 SH[SHW];

  int sq = blockIdx.x / G, g = blockIdx.x % G;
  int tid = threadIdx.x, lane = tid & 63, wv = tid >> 6;
  int m = lane & 15, quad = lane >> 4;

  const u16* Pg = P + (size_t)sq * L * Lp;
  constexpr int PU = L * Lp / 8;
  for (int u = tid; u < PU; u += 256){
    int r = u / (Lp/8), c = u % (Lp/8);
    *(short8*)(SH + r*LPP + c*8) = *(const short8*)(Pg + (size_t)r*Lp + c*8);
  }
  __syncthreads();

  short8 bfr[CJW][NKS];
  #pragma unroll
  for (int lc = 0; lc < CJW; lc++){
    const u16* vr = vt + ((size_t)sq*CC + (size_t)((g*NCJ + (wv*CJW + lc))*16 + m))*Lp + quad*8;
    #pragma unroll
    for (int ks = 0; ks < NKS; ks++) bfr[lc][ks] = *(const short8*)(vr + ks*32);
  }

  f32x4 acc[CJW][NTQ];
  #pragma unroll
  for (int lc = 0; lc < CJW; lc++)
    #pragma unroll
    for (int qt = 0; qt < NTQ; qt++) acc[lc][qt] = (f32x4){0.f,0.f,0.f,0.f};

  #pragma unroll
  for (int qt = 0; qt < NTQ; qt++){
    short8 a[NKS];
    #pragma unroll
    for (int ks = 0; ks < NKS; ks++)
      a[ks] = *(const short8*)(SH + (qt*16 + m)*LPP + quad*8 + ks*32);
    #pragma unroll
    for (int lc = 0; lc < CJW; lc++)
      #pragma unroll
      for (int ks = 0; ks < NKS; ks++)
        acc[lc][qt] = mfma_bf16(a[ks], bfr[lc][ks], acc[lc][qt]);
  }
  __syncthreads();

  #pragma unroll
  for (int qt = 0; qt < NTQ; qt++)
    #pragma unroll
    for (int lc = 0; lc < CJW; lc++)
      #pragma unroll
      for (int r = 0; r < 4; r++)
        SH[(qt*16 + quad*4 + r)*CW + (wv*CJW + lc)*16 + m] = f2bf(acc[lc][qt][r]);
  __syncthreads();

  size_t tokbase = (size_t)(sq/SD)*OUTs + (size_t)(sq%SD)*INN;
  constexpr int CU8 = CW / 8;
  constexpr int TU = L * CU8;
  for (int u = tid; u < TU; u += 256){
    int l = u / CU8, c = u % CU8;
    *(short8*)(ctx + (tokbase + (size_t)l*LST)*CC + g*CW + c*8) =
        *(const short8*)(SH + l*CW + c*8);
  }
}

// =======================================================================
extern "C" void kernel_launch(void* const* d_in, const int* in_sizes, int n_in,
                              void* d_out, int out_size, void* d_ws, size_t ws_size,
                              hipStream_t stream){
  const float* x      = (const float*)d_in[0];
  const float* wqkv1  = (const float*)d_in[1];
  const float* wout1  = (const float*)d_in[2];
  const float* wqkv2  = (const float*)d_in[3];
  const float* wout2  = (const float*)d_in[4];
  const float* g1 = (const float*)d_in[5];  const float* b1 = (const float*)d_in[6];
  const float* g2 = (const float*)d_in[7];  const float* b2 = (const float*)d_in[8];
  const float* g3 = (const float*)d_in[9];  const float* b3 = (const float*)d_in[10];
  const float* wfc1 = (const float*)d_in[11]; const float* bfc1 = (const float*)d_in[12];
  const float* wfc2 = (const float*)d_in[13]; const float* bfc2 = (const float*)d_in[14];

  // ---- workspace layout (461 MB total) ----
  char* ws = (char*)d_ws;
  size_t off = 0;
  auto alloc = [&](size_t bytes)->char*{
    char* p = ws + off; off += (bytes + 255) & ~(size_t)255; return p;
  };
  float* xres = (float*)alloc((size_t)NTOK*CC*4);            // 151.0 MB residual (f32)
  u16*   y    = (u16*)  alloc((size_t)NTOK*CC*2);            //  75.5 MB LN out / ctx
  u16*   qkv  = (u16*)  alloc((size_t)NTOK*1536*2);          // 226.5 MB q|k|v ; MLP h overlays
  u16* wqkv1p = (u16*)alloc((size_t)1536*512*2);
  u16* wqkv2p = (u16*)alloc((size_t)1536*512*2);
  u16* wout1p = (u16*)alloc((size_t)512*512*2);
  u16* wout2p = (u16*)alloc((size_t)512*512*2);
  u16* wfc1p  = (u16*)alloc((size_t)2048*512*2);
  u16* wfc2p  = (u16*)alloc((size_t)512*2048*2);
  u16*   hv   = qkv;                                         // MLP hidden half (151 MB <= 226.5 MB)

  // ---- d_out doubles as scratch (fully rewritten by k_tout at the end) ----
  u16*   P    = (u16*)d_out;
  u16*   vt   = (u16*)((char*)d_out + 28311552);
  float* S    = (float*)((char*)d_out + 28311552);
  (void)ws_size; (void)in_sizes; (void)n_in; (void)out_size;

  const float scale = 0.044194173824159216f;   // 1/sqrt(512)

  // weights
  k_permqkv<<<3072, 256, 0, stream>>>(wqkv1, wqkv1p);
  k_permqkv<<<3072, 256, 0, stream>>>(wqkv2, wqkv2p);
  k_conv<<<1024, 256, 0, stream>>>(wout1, wout1p, 512*512);
  k_conv<<<1024, 256, 0, stream>>>(wout2, wout2p, 512*512);
  k_conv<<<4096, 256, 0, stream>>>(wfc1, wfc1p, 2048*512);
  k_conv<<<4096, 256, 0, stream>>>(wfc2, wfc2p, 512*2048);

  // stage 0: layout
  k_tin<<<BB*HH*96, 256, 0, stream>>>(x, xres);

  // ---- attention 1 (along H; seq = (b,w), L=48) ----
  k_ln<<<NTOK/4, 256, 0, stream>>>(xres, g1, b1, y);
  k_gemm256<0><<<288*6, 512, 0, stream>>>(y, 512, wqkv1p, 512, qkv, 1536, nullptr, 512, 6);
  k_qk<<<1536*9, 64, 0, stream>>>(qkv, qkv+512, 1536, S, 48, 3, 192, 9216, 1, 192, scale);
  k_softmax<<<NTOK/4, 256, 0, stream>>>(S, P, 48, 64);
  k_vt<<<1536*16, 256, 0, stream>>>(qkv+1024, 1536, vt, 48, 64, 192, 9216, 1, 192);
  k_pv2<48,64,3,16><<<1536*2, 256, 0, stream>>>(P, vt, y, 192, 9216, 1, 192);
  k_gemm256<2><<<288*2, 512, 0, stream>>>(y, 512, wout1p, 512, xres, 512, nullptr, 512, 2);

  // ---- attention 2 (along W; seq = (b,h), L=192) ----
  k_ln<<<NTOK/4, 256, 0, stream>>>(xres, g2, b2, y);
  k_gemm256<0><<<288*6, 512, 0, stream>>>(y, 512, wqkv2p, 512, qkv, 1536, nullptr, 512, 6);
  k_qk<<<384*144, 64, 0, stream>>>(qkv, qkv+512, 1536, S, 192, 12, 48, 9216, 192, 1, scale);
  k_softmax<<<NTOK/4, 256, 0, stream>>>(S, P, 192, 192);
  k_vt<<<384*16, 256, 0, stream>>>(qkv+1024, 1536, vt, 192, 192, 48, 9216, 192, 1);
  k_pv2<192,192,12,8><<<384*4, 256, 0, stream>>>(P, vt, y, 48, 9216, 192, 1);
  k_gemm256<2><<<288*2, 512, 0, stream>>>(y, 512, wout2p, 512, xres, 512, nullptr, 512, 2);

  // ---- MLP: two M-halves, each fc1 (full N=2048) then fc2 (single K=2048 pass) ----
  k_ln<<<NTOK/4, 256, 0, stream>>>(xres, g3, b3, y);
  for (int half = 0; half < 2; half++){
    size_t M0 = (size_t)half * 36864;
    k_gemm256<1><<<144*8, 512, 0, stream>>>(y + M0*512, 512, wfc1p, 512, hv, 2048, bfc1, 512, 8);
    k_gemm256<2><<<144*2, 512, 0, stream>>>(hv, 2048, wfc2p, 2048, xres + M0*512, 512, bfc2, 2048, 2);
  }

  // output layout
  k_tout<<<BB*HH*96, 256, 0, stream>>>(xres, (float*)d_out);
}

// Round 2
// 2198.482 us; speedup vs baseline: 1.1227x; 1.1227x over previous
//
#include <hip/hip_runtime.h>

typedef unsigned short u16;
typedef __attribute__((ext_vector_type(8))) short short8;
typedef __attribute__((ext_vector_type(8))) __bf16 bf16x8;
typedef __attribute__((ext_vector_type(4))) float f32x4;

#define DEV __device__ __forceinline__

// ---------- scalar helpers ----------
DEV u16 f2bf(float f){ unsigned u = __float_as_uint(f); return (u16)((u + 0x7fffu + ((u>>16)&1u)) >> 16); }
DEV float bf2f(u16 h){ return __uint_as_float(((unsigned)h)<<16); }

DEV f32x4 mfma_bf16(short8 a, short8 b, f32x4 c){
  return __builtin_amdgcn_mfma_f32_16x16x32_bf16(
      __builtin_bit_cast(bf16x8, a), __builtin_bit_cast(bf16x8, b), c, 0, 0, 0);
}

DEV void gl2lds16(const u16* g, u16* s){
  __builtin_amdgcn_global_load_lds(
      (__attribute__((address_space(1))) void*)(g),
      (__attribute__((address_space(3))) void*)(s), 16, 0, 0);
}

// problem constants
#define BB 8
#define HH 48
#define WW 192
#define CC 512
#define NTOK (BB*HH*WW)        // 73728

// ---------- weight prep ----------
__global__ void k_permqkv(const float* __restrict__ w, u16* __restrict__ o){
  int i = blockIdx.x*256 + threadIdx.x;          // 1536*512 total
  int n = i >> 9, kk = i & 511;
  int src = 3*(n & 511) + (n >> 9);
  o[i] = f2bf(w[src*512 + kk]);
}
__global__ void k_conv(const float* __restrict__ w, u16* __restrict__ o, int nelem){
  int i = blockIdx.x*256 + threadIdx.x;
  if (i < nelem) o[i] = f2bf(w[i]);
}

// ---------- transpose in: x (B,C,H,W) f32 -> xres (B,H,W,C) f32 ----------
__global__ void k_tin(const float* __restrict__ x, float* __restrict__ xr){
  __shared__ float T[32][33];
  int bh = blockIdx.x / 96, rem = blockIdx.x % 96;
  int c0 = (rem/6)*32, w0 = (rem%6)*32;
  int b = bh / HH, h = bh % HH;
  const float* xp = x + ((size_t)b*CC*HH + h)*WW;     // + c*(HH*WW) + w
  #pragma unroll
  for (int p=0;p<4;p++){
    int idx = p*256 + threadIdx.x;
    int cc = idx >> 5, ww = idx & 31;
    T[cc][ww] = xp[(size_t)(c0+cc)*(HH*WW) + w0 + ww];
  }
  __syncthreads();
  float* xo = xr + (size_t)bh*WW*CC;
  #pragma unroll
  for (int p=0;p<4;p++){
    int idx = p*256 + threadIdx.x;
    int ww = idx >> 5, cc = idx & 31;
    xo[(size_t)(w0+ww)*CC + c0 + cc] = T[cc][ww];
  }
}

// ---------- transpose out: xres (B,H,W,C) f32 -> out (B,C,H,W) f32 ----------
__global__ void k_tout(const float* __restrict__ xr, float* __restrict__ out){
  __shared__ float T[32][33];
  int bh = blockIdx.x / 96, rem = blockIdx.x % 96;
  int c0 = (rem/6)*32, w0 = (rem%6)*32;
  int b = bh / HH, h = bh % HH;
  const float* xi = xr + (size_t)bh*WW*CC;
  #pragma unroll
  for (int p=0;p<4;p++){
    int idx = p*256 + threadIdx.x;
    int ww = idx >> 5, cc = idx & 31;
    T[ww][cc] = xi[(size_t)(w0+ww)*CC + c0 + cc];
  }
  __syncthreads();
  float* op = out + ((size_t)b*CC*HH + h)*WW;
  #pragma unroll
  for (int p=0;p<4;p++){
    int idx = p*256 + threadIdx.x;
    int cc = idx >> 5, ww = idx & 31;
    op[(size_t)(c0+cc)*(HH*WW) + w0 + ww] = T[ww][cc];
  }
}

// ---------- LayerNorm: xres f32 -> y bf16 (wave per token) ----------
__global__ void k_ln(const float* __restrict__ xr, const float* __restrict__ g,
                     const float* __restrict__ bb, u16* __restrict__ y){
  int t = blockIdx.x*4 + (threadIdx.x>>6);
  int lane = threadIdx.x & 63;
  const float* row = xr + (size_t)t*CC + lane*8;
  float v[8];
  *(f32x4*)(v)   = *(const f32x4*)(row);
  *(f32x4*)(v+4) = *(const f32x4*)(row+4);
  float s=0.f, s2=0.f;
  #pragma unroll
  for (int j=0;j<8;j++){ s += v[j]; s2 += v[j]*v[j]; }
  #pragma unroll
  for (int o=32;o;o>>=1){ s += __shfl_xor(s,o); s2 += __shfl_xor(s2,o); }
  float mean = s*(1.f/CC);
  float var  = s2*(1.f/CC) - mean*mean;
  float rs = rsqrtf(var + 1e-5f);
  const float* gp = g + lane*8; const float* bp = bb + lane*8;
  short8 o8;
  #pragma unroll
  for (int j=0;j<8;j++) o8[j] = (short)f2bf((v[j]-mean)*rs*gp[j] + bp[j]);
  *(short8*)(y + (size_t)t*CC + lane*8) = o8;
}

// ---------- GEMM: Out(M x N) = A(M x K) @ Bw(N x K)^T ----------
// BK=64, XOR-swizzled LDS (conflict-free ds_read_b128, global_load_lds-compatible).
// T1: chunked XCD-aware blockIdx swizzle — all nb-blocks sharing an A panel land
//     on the same XCD so the panel is fetched into one L2 (grids are %8==0).
// epi 0: store bf16 ; epi 1: store bf16 with bias+relu ; epi 2: f32 Out += acc (+bias)
__global__ __launch_bounds__(256)
void k_gemm(const u16* __restrict__ A, int lda,
            const u16* __restrict__ Bw, int ldb,
            void* __restrict__ Out, int ldo,
            const float* __restrict__ bias,
            int K, int nbn, int epi){
  __shared__ __align__(16) u16 As[128*64];
  __shared__ __align__(16) u16 Bs[128*64];
  // ---- XCD chunked swizzle (bijective: gridDim.x % 8 == 0 at all call sites) ----
  int cpx = gridDim.x >> 3;
  int l = (blockIdx.x & 7)*cpx + (blockIdx.x >> 3);
  int mb = l / nbn, nb = l % nbn;
  int tid = threadIdx.x, lane = tid & 63, wv = tid >> 6;
  size_t m0 = (size_t)mb*128, n0 = (size_t)nb*128;
  // staging: 8 rows per gl2lds16 call; lane -> row lr=lane>>3, swizzled chunk
  int lr = lane >> 3;                         // 0..7 (row within call)
  int cc0 = (lane & 7) ^ lr;                  // global 8-u16 chunk for this lane
  const u16* gA = A  + (m0 + wv*32 + lr)*(size_t)lda + cc0*8;
  const u16* gB = Bw + (n0 + wv*32 + lr)*(size_t)ldb + cc0*8;
  u16* sA = As + wv*32*64;
  u16* sB = Bs + wv*32*64;
  int m = lane & 15, quad = lane >> 4;
  int wm = (wv>>1)*64, wn = (wv&1)*64;
  // swizzled fragment column offsets (u16 units), per ks
  int off0 = ((quad    ) ^ (m & 7))*8;
  int off1 = ((quad + 4) ^ (m & 7))*8;
  f32x4 acc[4][4];
  #pragma unroll
  for (int i=0;i<4;i++)
    #pragma unroll
    for (int j=0;j<4;j++) acc[i][j] = (f32x4){0.f,0.f,0.f,0.f};
  const u16* aB = As + (wm + m)*64;
  const u16* bB = Bs + (wn + m)*64;
  for (int k0 = 0; k0 < K; k0 += 64){
    #pragma unroll
    for (int t=0;t<4;t++){
      gl2lds16(gA + (size_t)(t*8)*lda, sA + t*8*64);
      gl2lds16(gB + (size_t)(t*8)*ldb, sB + t*8*64);
    }
    gA += 64; gB += 64;
    __syncthreads();
    {
      short8 af[4], bf[4];
      #pragma unroll
      for (int i=0;i<4;i++) af[i] = *(const short8*)(aB + i*16*64 + off0);
      #pragma unroll
      for (int j=0;j<4;j++) bf[j] = *(const short8*)(bB + j*16*64 + off0);
      #pragma unroll
      for (int i=0;i<4;i++)
        #pragma unroll
        for (int j=0;j<4;j++)
          acc[i][j] = mfma_bf16(af[i], bf[j], acc[i][j]);
    }
    {
      short8 af[4], bf[4];
      #pragma unroll
      for (int i=0;i<4;i++) af[i] = *(const short8*)(aB + i*16*64 + off1);
      #pragma unroll
      for (int j=0;j<4;j++) bf[j] = *(const short8*)(bB + j*16*64 + off1);
      #pragma unroll
      for (int i=0;i<4;i++)
        #pragma unroll
        for (int j=0;j<4;j++)
          acc[i][j] = mfma_bf16(af[i], bf[j], acc[i][j]);
    }
    __syncthreads();
  }
  if (epi == 2){
    float* O = (float*)Out + (m0 + wm + quad*4)*(size_t)ldo + n0 + wn + m;
    #pragma unroll
    for (int j=0;j<4;j++){
      float bv = bias ? bias[n0 + wn + j*16 + m] : 0.f;
      #pragma unroll
      for (int i=0;i<4;i++)
        #pragma unroll
        for (int r=0;r<4;r++)
          O[(size_t)(i*16+r)*ldo + j*16] += acc[i][j][r] + bv;
    }
  } else {
    u16* O = (u16*)Out + (m0 + wm + quad*4)*(size_t)ldo + n0 + wn + m;
    #pragma unroll
    for (int j=0;j<4;j++){
      float bv = bias ? bias[n0 + wn + j*16 + m] : 0.f;
      #pragma unroll
      for (int i=0;i<4;i++)
        #pragma unroll
        for (int r=0;r<4;r++){
          float v = acc[i][j][r] + bv;
          if (epi == 1) v = fmaxf(v, 0.f);
          O[(size_t)(i*16+r)*ldo + j*16] = f2bf(v);
        }
    }
  }
}

// ---------- QK^T: one wave per 16x16 S tile ----------
__global__ void k_qk(const u16* __restrict__ q, const u16* __restrict__ kp, int ldq,
                     float* __restrict__ S, int L, int nt,
                     int SD, int OUTs, int INN, int LST, float scale){
  int blk = blockIdx.x;
  int s = blk / (nt*nt), tl = blk % (nt*nt);
  int ti = tl / nt, tj = tl % nt;
  int lane = threadIdx.x, m = lane & 15, quad = lane >> 4;
  size_t tokbase = (size_t)(s/SD)*OUTs + (size_t)(s%SD)*INN;
  const u16* qr = q  + (tokbase + (size_t)(ti*16+m)*LST)*ldq + quad*8;
  const u16* kr = kp + (tokbase + (size_t)(tj*16+m)*LST)*ldq + quad*8;
  f32x4 acc = (f32x4){0.f,0.f,0.f,0.f};
  #pragma unroll
  for (int kk=0; kk<CC; kk+=32)
    acc = mfma_bf16(*(const short8*)(qr+kk), *(const short8*)(kr+kk), acc);
  float* Sp = S + (size_t)s*L*L + (size_t)(ti*16 + quad*4)*L + tj*16 + m;
  #pragma unroll
  for (int r=0;r<4;r++) Sp[(size_t)r*L] = acc[r]*scale;
}

// ---------- softmax rows (wave per row), write bf16 P padded to Lp ----------
__global__ void k_softmax(const float* __restrict__ S, u16* __restrict__ P, int L, int Lp){
  int row = blockIdx.x*4 + (threadIdx.x>>6);
  int lane = threadIdx.x & 63;
  const float* sr = S + (size_t)row*L;
  float v0 = (lane      < L) ? sr[lane]      : -3.0e38f;
  float v1 = (lane+64   < L) ? sr[lane+64]   : -3.0e38f;
  float v2 = (lane+128  < L) ? sr[lane+128]  : -3.0e38f;
  float mx = fmaxf(v0, fmaxf(v1, v2));
  #pragma unroll
  for (int o=32;o;o>>=1) mx = fmaxf(mx, __shfl_xor(mx, o));
  float e0 = (lane      < L) ? __expf(v0-mx) : 0.f;
  float e1 = (lane+64   < L) ? __expf(v1-mx) : 0.f;
  float e2 = (lane+128  < L) ? __expf(v2-mx) : 0.f;
  float sm = e0+e1+e2;
  #pragma unroll
  for (int o=32;o;o>>=1) sm += __shfl_xor(sm, o);
  float inv = 1.f/sm;
  u16* pr = P + (size_t)row*Lp;
  if (lane      < Lp) pr[lane]      = f2bf(e0*inv);
  if (lane+64   < Lp) pr[lane+64]   = f2bf(e1*inv);
  if (lane+128  < Lp) pr[lane+128]  = f2bf(e2*inv);
}

// ---------- V transpose per sequence: v rows (l,c) -> vt[s][c][l], zero-pad l to Lp ----------
__global__ void k_vt(const u16* __restrict__ v, int ldv, u16* __restrict__ vt,
                     int L, int Lp, int SD, int OUTs, int INN, int LST){
  __shared__ float T[32*193];
  int s = blockIdx.x >> 4;
  int c0 = (blockIdx.x & 15)*32;
  size_t tokbase = (size_t)(s/SD)*OUTs + (size_t)(s%SD)*INN;
  int pad = Lp + 1;
  for (int idx = threadIdx.x; idx < L*32; idx += 256){
    int l = idx >> 5, cc = idx & 31;
    T[cc*pad + l] = bf2f(v[(tokbase + (size_t)l*LST)*ldv + c0 + cc]);
  }
  __syncthreads();
  u16* vo = vt + ((size_t)s*CC + c0)*Lp;
  for (int idx = threadIdx.x; idx < 32*Lp; idx += 256){
    int cc = idx / Lp, l = idx - cc*Lp;
    vo[idx] = (l < L) ? f2bf(T[cc*pad + l]) : (u16)0;
  }
}

// ---------- PV v2: block (256 thr) per (seq, column-group) with LDS staging ----------
template<int L, int Lp, int NTQ, int NCJ>
__global__ __launch_bounds__(256)
void k_pv2(const u16* __restrict__ P, const u16* __restrict__ vt, u16* __restrict__ ctx,
           int SD, int OUTs, int INN, int LST){
  constexpr int G   = 32 / NCJ;          // blocks per sequence
  constexpr int LPP = Lp + 8;            // padded P row stride (u16)
  constexpr int CW  = NCJ * 16;          // ctx columns per block
  constexpr int CJW = NCJ / 4;           // cj tiles per wave
  constexpr int NKS = Lp / 32;           // K steps per MFMA chain
  constexpr int SHW = (L*LPP > L*CW) ? L*LPP : L*CW;
  __shared__ __align__(16) u16 SH[SHW];

  int sq = blockIdx.x / G, g = blockIdx.x % G;
  int tid = threadIdx.x, lane = tid & 63, wv = tid >> 6;
  int m = lane & 15, quad = lane >> 4;

  const u16* Pg = P + (size_t)sq * L * Lp;
  constexpr int PU = L * Lp / 8;
  for (int u = tid; u < PU; u += 256){
    int r = u / (Lp/8), c = u % (Lp/8);
    *(short8*)(SH + r*LPP + c*8) = *(const short8*)(Pg + (size_t)r*Lp + c*8);
  }
  __syncthreads();

  short8 bfr[CJW][NKS];
  #pragma unroll
  for (int lc = 0; lc < CJW; lc++){
    const u16* vr = vt + ((size_t)sq*CC + (size_t)((g*NCJ + (wv*CJW + lc))*16 + m))*Lp + quad*8;
    #pragma unroll
    for (int ks = 0; ks < NKS; ks++) bfr[lc][ks] = *(const short8*)(vr + ks*32);
  }

  f32x4 acc[CJW][NTQ];
  #pragma unroll
  for (int lc = 0; lc < CJW; lc++)
    #pragma unroll
    for (int qt = 0; qt < NTQ; qt++) acc[lc][qt] = (f32x4){0.f,0.f,0.f,0.f};

  #pragma unroll
  for (int qt = 0; qt < NTQ; qt++){
    short8 a[NKS];
    #pragma unroll
    for (int ks = 0; ks < NKS; ks++)
      a[ks] = *(const short8*)(SH + (qt*16 + m)*LPP + quad*8 + ks*32);
    #pragma unroll
    for (int lc = 0; lc < CJW; lc++)
      #pragma unroll
      for (int ks = 0; ks < NKS; ks++)
        acc[lc][qt] = mfma_bf16(a[ks], bfr[lc][ks], acc[lc][qt]);
  }
  __syncthreads();

  #pragma unroll
  for (int qt = 0; qt < NTQ; qt++)
    #pragma unroll
    for (int lc = 0; lc < CJW; lc++)
      #pragma unroll
      for (int r = 0; r < 4; r++)
        SH[(qt*16 + quad*4 + r)*CW + (wv*CJW + lc)*16 + m] = f2bf(acc[lc][qt][r]);
  __syncthreads();

  size_t tokbase = (size_t)(sq/SD)*OUTs + (size_t)(sq%SD)*INN;
  constexpr int CU8 = CW / 8;
  constexpr int TU = L * CU8;
  for (int u = tid; u < TU; u += 256){
    int l = u / CU8, c = u % CU8;
    *(short8*)(ctx + (tokbase + (size_t)l*LST)*CC + g*CW + c*8) =
        *(const short8*)(SH + l*CW + c*8);
  }
}

// =======================================================================
extern "C" void kernel_launch(void* const* d_in, const int* in_sizes, int n_in,
                              void* d_out, int out_size, void* d_ws, size_t ws_size,
                              hipStream_t stream){
  const float* x      = (const float*)d_in[0];
  const float* wqkv1  = (const float*)d_in[1];
  const float* wout1  = (const float*)d_in[2];
  const float* wqkv2  = (const float*)d_in[3];
  const float* wout2  = (const float*)d_in[4];
  const float* g1 = (const float*)d_in[5];  const float* b1 = (const float*)d_in[6];
  const float* g2 = (const float*)d_in[7];  const float* b2 = (const float*)d_in[8];
  const float* g3 = (const float*)d_in[9];  const float* b3 = (const float*)d_in[10];
  const float* wfc1 = (const float*)d_in[11]; const float* bfc1 = (const float*)d_in[12];
  const float* wfc2 = (const float*)d_in[13]; const float* bfc2 = (const float*)d_in[14];

  // ---- workspace layout (461 MB total) ----
  char* ws = (char*)d_ws;
  size_t off = 0;
  auto alloc = [&](size_t bytes)->char*{
    char* p = ws + off; off += (bytes + 255) & ~(size_t)255; return p;
  };
  float* xres = (float*)alloc((size_t)NTOK*CC*4);            // 151.0 MB residual (f32)
  u16*   y    = (u16*)  alloc((size_t)NTOK*CC*2);            //  75.5 MB LN out / ctx
  u16*   qkv  = (u16*)  alloc((size_t)NTOK*1536*2);          // 226.5 MB q|k|v ; MLP h overlays
  u16* wqkv1p = (u16*)alloc((size_t)1536*512*2);
  u16* wqkv2p = (u16*)alloc((size_t)1536*512*2);
  u16* wout1p = (u16*)alloc((size_t)512*512*2);
  u16* wout2p = (u16*)alloc((size_t)512*512*2);
  u16* wfc1p  = (u16*)alloc((size_t)2048*512*2);
  u16* wfc2p  = (u16*)alloc((size_t)512*2048*2);
  u16*   hv   = qkv;                                         // MLP hidden half (151 MB <= 226.5 MB)

  // ---- d_out doubles as scratch (fully rewritten by k_tout at the end) ----
  u16*   P    = (u16*)d_out;
  u16*   vt   = (u16*)((char*)d_out + 28311552);
  float* S    = (float*)((char*)d_out + 28311552);
  (void)ws_size; (void)in_sizes; (void)n_in; (void)out_size;

  const float scale = 0.044194173824159216f;   // 1/sqrt(512)

  // weights
  k_permqkv<<<3072, 256, 0, stream>>>(wqkv1, wqkv1p);
  k_permqkv<<<3072, 256, 0, stream>>>(wqkv2, wqkv2p);
  k_conv<<<1024, 256, 0, stream>>>(wout1, wout1p, 512*512);
  k_conv<<<1024, 256, 0, stream>>>(wout2, wout2p, 512*512);
  k_conv<<<4096, 256, 0, stream>>>(wfc1, wfc1p, 2048*512);
  k_conv<<<4096, 256, 0, stream>>>(wfc2, wfc2p, 512*2048);

  // stage 0: layout
  k_tin<<<BB*HH*96, 256, 0, stream>>>(x, xres);

  // ---- attention 1 (along H; seq = (b,w), L=48) ----
  k_ln<<<NTOK/4, 256, 0, stream>>>(xres, g1, b1, y);
  k_gemm<<<576*12, 256, 0, stream>>>(y, 512, wqkv1p, 512, qkv, 1536, nullptr, 512, 12, 0);
  k_qk<<<1536*9, 64, 0, stream>>>(qkv, qkv+512, 1536, S, 48, 3, 192, 9216, 1, 192, scale);
  k_softmax<<<NTOK/4, 256, 0, stream>>>(S, P, 48, 64);
  k_vt<<<1536*16, 256, 0, stream>>>(qkv+1024, 1536, vt, 48, 64, 192, 9216, 1, 192);
  k_pv2<48,64,3,16><<<1536*2, 256, 0, stream>>>(P, vt, y, 192, 9216, 1, 192);
  k_gemm<<<576*4, 256, 0, stream>>>(y, 512, wout1p, 512, xres, 512, nullptr, 512, 4, 2);

  // ---- attention 2 (along W; seq = (b,h), L=192) ----
  k_ln<<<NTOK/4, 256, 0, stream>>>(xres, g2, b2, y);
  k_gemm<<<576*12, 256, 0, stream>>>(y, 512, wqkv2p, 512, qkv, 1536, nullptr, 512, 12, 0);
  k_qk<<<384*144, 64, 0, stream>>>(qkv, qkv+512, 1536, S, 192, 12, 48, 9216, 192, 1, scale);
  k_softmax<<<NTOK/4, 256, 0, stream>>>(S, P, 192, 192);
  k_vt<<<384*16, 256, 0, stream>>>(qkv+1024, 1536, vt, 192, 192, 48, 9216, 192, 1);
  k_pv2<192,192,12,8><<<384*4, 256, 0, stream>>>(P, vt, y, 48, 9216, 192, 1);
  k_gemm<<<576*4, 256, 0, stream>>>(y, 512, wout2p, 512, xres, 512, nullptr, 512, 4, 2);

  // ---- MLP: two M-halves, each fc1 (full N=2048) then fc2 (single K=2048 pass) ----
  k_ln<<<NTOK/4, 256, 0, stream>>>(xres, g3, b3, y);
  for (int half = 0; half < 2; half++){
    size_t M0 = (size_t)half * 36864;
    k_gemm<<<288*16, 256, 0, stream>>>(y + M0*512, 512, wfc1p, 512, hv, 2048, bfc1, 512, 16, 1);
    k_gemm<<<288*4, 256, 0, stream>>>(hv, 2048, wfc2p, 2048, xres + M0*512, 512, bfc2, 2048, 4, 2);
  }

  // output layout
  k_tout<<<BB*HH*96, 256, 0, stream>>>(xres, (float*)d_out);
}

// Round 3
// 2008.643 us; speedup vs baseline: 1.2288x; 1.0945x over previous
//
#include <hip/hip_runtime.h>

typedef unsigned short u16;
typedef __attribute__((ext_vector_type(8))) short short8;
typedef __attribute__((ext_vector_type(8))) __bf16 bf16x8;
typedef __attribute__((ext_vector_type(4))) float f32x4;

#define DEV __device__ __forceinline__

// ---------- scalar helpers ----------
DEV u16 f2bf(float f){ unsigned u = __float_as_uint(f); return (u16)((u + 0x7fffu + ((u>>16)&1u)) >> 16); }
DEV float bf2f(u16 h){ return __uint_as_float(((unsigned)h)<<16); }

DEV f32x4 mfma_bf16(short8 a, short8 b, f32x4 c){
  return __builtin_amdgcn_mfma_f32_16x16x32_bf16(
      __builtin_bit_cast(bf16x8, a), __builtin_bit_cast(bf16x8, b), c, 0, 0, 0);
}

DEV void gl2lds16(const u16* g, u16* s){
  __builtin_amdgcn_global_load_lds(
      (__attribute__((address_space(1))) void*)(g),
      (__attribute__((address_space(3))) void*)(s), 16, 0, 0);
}

// problem constants
#define BB 8
#define HH 48
#define WW 192
#define CC 512
#define NTOK (BB*HH*WW)        // 73728

// ---------- weight prep ----------
__global__ void k_permqkv(const float* __restrict__ w, u16* __restrict__ o){
  int i = blockIdx.x*256 + threadIdx.x;          // 1536*512 total
  int n = i >> 9, kk = i & 511;
  int src = 3*(n & 511) + (n >> 9);
  o[i] = f2bf(w[src*512 + kk]);
}
__global__ void k_conv(const float* __restrict__ w, u16* __restrict__ o, int nelem){
  int i = blockIdx.x*256 + threadIdx.x;
  if (i < nelem) o[i] = f2bf(w[i]);
}

// ---------- transpose in: x (B,C,H,W) f32 -> xres (B,H,W,C) f32 ----------
__global__ void k_tin(const float* __restrict__ x, float* __restrict__ xr){
  __shared__ float T[32][33];
  int bh = blockIdx.x / 96, rem = blockIdx.x % 96;
  int c0 = (rem/6)*32, w0 = (rem%6)*32;
  int b = bh / HH, h = bh % HH;
  const float* xp = x + ((size_t)b*CC*HH + h)*WW;     // + c*(HH*WW) + w
  #pragma unroll
  for (int p=0;p<4;p++){
    int idx = p*256 + threadIdx.x;
    int cc = idx >> 5, ww = idx & 31;
    T[cc][ww] = xp[(size_t)(c0+cc)*(HH*WW) + w0 + ww];
  }
  __syncthreads();
  float* xo = xr + (size_t)bh*WW*CC;
  #pragma unroll
  for (int p=0;p<4;p++){
    int idx = p*256 + threadIdx.x;
    int ww = idx >> 5, cc = idx & 31;
    xo[(size_t)(w0+ww)*CC + c0 + cc] = T[cc][ww];
  }
}

// ---------- transpose out: xres (B,H,W,C) f32 -> out (B,C,H,W) f32 ----------
__global__ void k_tout(const float* __restrict__ xr, float* __restrict__ out){
  __shared__ float T[32][33];
  int bh = blockIdx.x / 96, rem = blockIdx.x % 96;
  int c0 = (rem/6)*32, w0 = (rem%6)*32;
  int b = bh / HH, h = bh % HH;
  const float* xi = xr + (size_t)bh*WW*CC;
  #pragma unroll
  for (int p=0;p<4;p++){
    int idx = p*256 + threadIdx.x;
    int ww = idx >> 5, cc = idx & 31;
    T[ww][cc] = xi[(size_t)(w0+ww)*CC + c0 + cc];
  }
  __syncthreads();
  float* op = out + ((size_t)b*CC*HH + h)*WW;
  #pragma unroll
  for (int p=0;p<4;p++){
    int idx = p*256 + threadIdx.x;
    int cc = idx >> 5, ww = idx & 31;
    op[(size_t)(c0+cc)*(HH*WW) + w0 + ww] = T[ww][cc];
  }
}

// ---------- LayerNorm: xres f32 -> y bf16 (wave per token) ----------
__global__ void k_ln(const float* __restrict__ xr, const float* __restrict__ g,
                     const float* __restrict__ bb, u16* __restrict__ y){
  int t = blockIdx.x*4 + (threadIdx.x>>6);
  int lane = threadIdx.x & 63;
  const float* row = xr + (size_t)t*CC + lane*8;
  float v[8];
  *(f32x4*)(v)   = *(const f32x4*)(row);
  *(f32x4*)(v+4) = *(const f32x4*)(row+4);
  float s=0.f, s2=0.f;
  #pragma unroll
  for (int j=0;j<8;j++){ s += v[j]; s2 += v[j]*v[j]; }
  #pragma unroll
  for (int o=32;o;o>>=1){ s += __shfl_xor(s,o); s2 += __shfl_xor(s2,o); }
  float mean = s*(1.f/CC);
  float var  = s2*(1.f/CC) - mean*mean;
  float rs = rsqrtf(var + 1e-5f);
  const float* gp = g + lane*8; const float* bp = bb + lane*8;
  short8 o8;
  #pragma unroll
  for (int j=0;j<8;j++) o8[j] = (short)f2bf((v[j]-mean)*rs*gp[j] + bp[j]);
  *(short8*)(y + (size_t)t*CC + lane*8) = o8;
}

// ---------- GEMM: Out(M x N) = A(M x K) @ Bw(N x K)^T ----------
// BK=64, XOR-swizzled LDS (conflict-free ds_read_b128, global_load_lds-compatible).
// T1: chunked XCD-aware blockIdx swizzle.
// epi 0: store bf16 ; epi 1: store bf16 with bias+relu ; epi 2: f32 Out += acc (+bias)
__global__ __launch_bounds__(256)
void k_gemm(const u16* __restrict__ A, int lda,
            const u16* __restrict__ Bw, int ldb,
            void* __restrict__ Out, int ldo,
            const float* __restrict__ bias,
            int K, int nbn, int epi){
  __shared__ __align__(16) u16 As[128*64];
  __shared__ __align__(16) u16 Bs[128*64];
  // ---- XCD chunked swizzle (bijective: gridDim.x % 8 == 0 at all call sites) ----
  int cpx = gridDim.x >> 3;
  int l = (blockIdx.x & 7)*cpx + (blockIdx.x >> 3);
  int mb = l / nbn, nb = l % nbn;
  int tid = threadIdx.x, lane = tid & 63, wv = tid >> 6;
  size_t m0 = (size_t)mb*128, n0 = (size_t)nb*128;
  // staging: 8 rows per gl2lds16 call; lane -> row lr=lane>>3, swizzled chunk
  int lr = lane >> 3;                         // 0..7 (row within call)
  int cc0 = (lane & 7) ^ lr;                  // global 8-u16 chunk for this lane
  const u16* gA = A  + (m0 + wv*32 + lr)*(size_t)lda + cc0*8;
  const u16* gB = Bw + (n0 + wv*32 + lr)*(size_t)ldb + cc0*8;
  u16* sA = As + wv*32*64;
  u16* sB = Bs + wv*32*64;
  int m = lane & 15, quad = lane >> 4;
  int wm = (wv>>1)*64, wn = (wv&1)*64;
  // swizzled fragment column offsets (u16 units), per ks
  int off0 = ((quad    ) ^ (m & 7))*8;
  int off1 = ((quad + 4) ^ (m & 7))*8;
  f32x4 acc[4][4];
  #pragma unroll
  for (int i=0;i<4;i++)
    #pragma unroll
    for (int j=0;j<4;j++) acc[i][j] = (f32x4){0.f,0.f,0.f,0.f};
  const u16* aB = As + (wm + m)*64;
  const u16* bB = Bs + (wn + m)*64;
  for (int k0 = 0; k0 < K; k0 += 64){
    #pragma unroll
    for (int t=0;t<4;t++){
      gl2lds16(gA + (size_t)(t*8)*lda, sA + t*8*64);
      gl2lds16(gB + (size_t)(t*8)*ldb, sB + t*8*64);
    }
    gA += 64; gB += 64;
    __syncthreads();
    {
      short8 af[4], bf[4];
      #pragma unroll
      for (int i=0;i<4;i++) af[i] = *(const short8*)(aB + i*16*64 + off0);
      #pragma unroll
      for (int j=0;j<4;j++) bf[j] = *(const short8*)(bB + j*16*64 + off0);
      #pragma unroll
      for (int i=0;i<4;i++)
        #pragma unroll
        for (int j=0;j<4;j++)
          acc[i][j] = mfma_bf16(af[i], bf[j], acc[i][j]);
    }
    {
      short8 af[4], bf[4];
      #pragma unroll
      for (int i=0;i<4;i++) af[i] = *(const short8*)(aB + i*16*64 + off1);
      #pragma unroll
      for (int j=0;j<4;j++) bf[j] = *(const short8*)(bB + j*16*64 + off1);
      #pragma unroll
      for (int i=0;i<4;i++)
        #pragma unroll
        for (int j=0;j<4;j++)
          acc[i][j] = mfma_bf16(af[i], bf[j], acc[i][j]);
    }
    __syncthreads();
  }
  if (epi == 2){
    float* O = (float*)Out + (m0 + wm + quad*4)*(size_t)ldo + n0 + wn + m;
    #pragma unroll
    for (int j=0;j<4;j++){
      float bv = bias ? bias[n0 + wn + j*16 + m] : 0.f;
      #pragma unroll
      for (int i=0;i<4;i++)
        #pragma unroll
        for (int r=0;r<4;r++)
          O[(size_t)(i*16+r)*ldo + j*16] += acc[i][j][r] + bv;
    }
  } else {
    u16* O = (u16*)Out + (m0 + wm + quad*4)*(size_t)ldo + n0 + wn + m;
    #pragma unroll
    for (int j=0;j<4;j++){
      float bv = bias ? bias[n0 + wn + j*16 + m] : 0.f;
      #pragma unroll
      for (int i=0;i<4;i++)
        #pragma unroll
        for (int r=0;r<4;r++){
          float v = acc[i][j][r] + bv;
          if (epi == 1) v = fmaxf(v, 0.f);
          O[(size_t)(i*16+r)*ldo + j*16] = f2bf(v);
        }
    }
  }
}

// ---------- QK^T v2: block per (seq, RPB-row Q strip); Q in regs, K via LDS ----------
// L: seq len; RPB: Q rows per block (NW=RPB/16 waves); KCH: K rows staged per chunk.
// K staged with XOR pre-swizzled global source (T2/rule21) -> conflict-free ds_read_b128.
// T1 chunked XCD swizzle keeps a sequence's strips on one XCD (K L2-shared).
template<int L, int RPB, int KCH, int NW>
__global__ __launch_bounds__(64*NW)
void k_qk2(const u16* __restrict__ q, const u16* __restrict__ kp, int ldq,
           float* __restrict__ S, int SD, int OUTs, int INN, int LST, float scale){
  constexpr int NSTRIP = L / RPB;
  constexpr int NCH = L / KCH;
  constexpr int RPW = KCH / NW;          // staged rows per wave per chunk
  constexpr int NJT = KCH / 16;          // j sub-tiles per chunk
  __shared__ __align__(16) u16 Ks[KCH*512];
  int cpx = gridDim.x >> 3;
  int bl = (blockIdx.x & 7)*cpx + (blockIdx.x >> 3);
  int s = bl / NSTRIP, st = bl % NSTRIP;
  int lane = threadIdx.x & 63, wv = threadIdx.x >> 6;
  int m = lane & 15, quad = lane >> 4;
  size_t tokbase = (size_t)(s/SD)*OUTs + (size_t)(s%SD)*INN;

  // Q strip rows -> registers (16 x short8 per lane)
  const u16* qr = q + (tokbase + (size_t)(st*RPB + wv*16 + m)*LST)*ldq + quad*8;
  short8 qf[16];
  #pragma unroll
  for (int kk=0;kk<16;kk++) qf[kk] = *(const short8*)(qr + kk*32);

  float* Sp = S + (size_t)s*L*L + (size_t)(st*RPB + wv*16 + quad*4)*L;

  for (int ch = 0; ch < NCH; ch++){
    // stage KCH K-rows; one row per gl2lds16 call (64 lanes x 16B = 1024B row)
    #pragma unroll
    for (int rr = 0; rr < RPW; rr++){
      int row = wv*RPW + rr;
      gl2lds16(kp + (tokbase + (size_t)(ch*KCH + row)*LST)*ldq + (lane ^ (row & 7))*8,
               Ks + row*512);
    }
    asm volatile("s_waitcnt vmcnt(0)" ::: "memory");
    __syncthreads();

    f32x4 acc[NJT];
    #pragma unroll
    for (int jt=0;jt<NJT;jt++) acc[jt] = (f32x4){0.f,0.f,0.f,0.f};
    const u16* kB = Ks + m*512;
    #pragma unroll
    for (int kk=0;kk<16;kk++){
      int chunk = ((quad + kk*4) ^ (m & 7))*8;     // swizzled u16 offset in row
      #pragma unroll
      for (int jt=0;jt<NJT;jt++){
        short8 bf = *(const short8*)(kB + jt*16*512 + chunk);
        acc[jt] = mfma_bf16(qf[kk], bf, acc[jt]);
      }
    }
    #pragma unroll
    for (int jt=0;jt<NJT;jt++)
      #pragma unroll
      for (int r=0;r<4;r++)
        Sp[(size_t)r*L + ch*KCH + jt*16 + m] = acc[jt][r]*scale;
    if (ch + 1 < NCH) __syncthreads();
  }
}

// ---------- softmax rows (wave per row), write bf16 P padded to Lp ----------
__global__ void k_softmax(const float* __restrict__ S, u16* __restrict__ P, int L, int Lp){
  int row = blockIdx.x*4 + (threadIdx.x>>6);
  int lane = threadIdx.x & 63;
  const float* sr = S + (size_t)row*L;
  float v0 = (lane      < L) ? sr[lane]      : -3.0e38f;
  float v1 = (lane+64   < L) ? sr[lane+64]   : -3.0e38f;
  float v2 = (lane+128  < L) ? sr[lane+128]  : -3.0e38f;
  float mx = fmaxf(v0, fmaxf(v1, v2));
  #pragma unroll
  for (int o=32;o;o>>=1) mx = fmaxf(mx, __shfl_xor(mx, o));
  float e0 = (lane      < L) ? __expf(v0-mx) : 0.f;
  float e1 = (lane+64   < L) ? __expf(v1-mx) : 0.f;
  float e2 = (lane+128  < L) ? __expf(v2-mx) : 0.f;
  float sm = e0+e1+e2;
  #pragma unroll
  for (int o=32;o;o>>=1) sm += __shfl_xor(sm, o);
  float inv = 1.f/sm;
  u16* pr = P + (size_t)row*Lp;
  if (lane      < Lp) pr[lane]      = f2bf(e0*inv);
  if (lane+64   < Lp) pr[lane+64]   = f2bf(e1*inv);
  if (lane+128  < Lp) pr[lane+128]  = f2bf(e2*inv);
}

// ---------- V transpose per sequence: v rows (l,c) -> vt[s][c][l], zero-pad l to Lp ----------
__global__ void k_vt(const u16* __restrict__ v, int ldv, u16* __restrict__ vt,
                     int L, int Lp, int SD, int OUTs, int INN, int LST){
  __shared__ float T[32*193];
  int s = blockIdx.x >> 4;
  int c0 = (blockIdx.x & 15)*32;
  size_t tokbase = (size_t)(s/SD)*OUTs + (size_t)(s%SD)*INN;
  int pad = Lp + 1;
  for (int idx = threadIdx.x; idx < L*32; idx += 256){
    int l = idx >> 5, cc = idx & 31;
    T[cc*pad + l] = bf2f(v[(tokbase + (size_t)l*LST)*ldv + c0 + cc]);
  }
  __syncthreads();
  u16* vo = vt + ((size_t)s*CC + c0)*Lp;
  for (int idx = threadIdx.x; idx < 32*Lp; idx += 256){
    int cc = idx / Lp, l = idx - cc*Lp;
    vo[idx] = (l < L) ? f2bf(T[cc*pad + l]) : (u16)0;
  }
}

// ---------- PV v2: block (256 thr) per (seq, column-group) with LDS staging ----------
template<int L, int Lp, int NTQ, int NCJ>
__global__ __launch_bounds__(256)
void k_pv2(const u16* __restrict__ P, const u16* __restrict__ vt, u16* __restrict__ ctx,
           int SD, int OUTs, int INN, int LST){
  constexpr int G   = 32 / NCJ;          // blocks per sequence
  constexpr int LPP = Lp + 8;            // padded P row stride (u16)
  constexpr int CW  = NCJ * 16;          // ctx columns per block
  constexpr int CJW = NCJ / 4;           // cj tiles per wave
  constexpr int NKS = Lp / 32;           // K steps per MFMA chain
  constexpr int SHW = (L*LPP > L*CW) ? L*LPP : L*CW;
  __shared__ __align__(16) u16 SH[SHW];

  int sq = blockIdx.x / G, g = blockIdx.x % G;
  int tid = threadIdx.x, lane = tid & 63, wv = tid >> 6;
  int m = lane & 15, quad = lane >> 4;

  const u16* Pg = P + (size_t)sq * L * Lp;
  constexpr int PU = L * Lp / 8;
  for (int u = tid; u < PU; u += 256){
    int r = u / (Lp/8), c = u % (Lp/8);
    *(short8*)(SH + r*LPP + c*8) = *(const short8*)(Pg + (size_t)r*Lp + c*8);
  }
  __syncthreads();

  short8 bfr[CJW][NKS];
  #pragma unroll
  for (int lc = 0; lc < CJW; lc++){
    const u16* vr = vt + ((size_t)sq*CC + (size_t)((g*NCJ + (wv*CJW + lc))*16 + m))*Lp + quad*8;
    #pragma unroll
    for (int ks = 0; ks < NKS; ks++) bfr[lc][ks] = *(const short8*)(vr + ks*32);
  }

  f32x4 acc[CJW][NTQ];
  #pragma unroll
  for (int lc = 0; lc < CJW; lc++)
    #pragma unroll
    for (int qt = 0; qt < NTQ; qt++) acc[lc][qt] = (f32x4){0.f,0.f,0.f,0.f};

  #pragma unroll
  for (int qt = 0; qt < NTQ; qt++){
    short8 a[NKS];
    #pragma unroll
    for (int ks = 0; ks < NKS; ks++)
      a[ks] = *(const short8*)(SH + (qt*16 + m)*LPP + quad*8 + ks*32);
    #pragma unroll
    for (int lc = 0; lc < CJW; lc++)
      #pragma unroll
      for (int ks = 0; ks < NKS; ks++)
        acc[lc][qt] = mfma_bf16(a[ks], bfr[lc][ks], acc[lc][qt]);
  }
  __syncthreads();

  #pragma unroll
  for (int qt = 0; qt < NTQ; qt++)
    #pragma unroll
    for (int lc = 0; lc < CJW; lc++)
      #pragma unroll
      for (int r = 0; r < 4; r++)
        SH[(qt*16 + quad*4 + r)*CW + (wv*CJW + lc)*16 + m] = f2bf(acc[lc][qt][r]);
  __syncthreads();

  size_t tokbase = (size_t)(sq/SD)*OUTs + (size_t)(sq%SD)*INN;
  constexpr int CU8 = CW / 8;
  constexpr int TU = L * CU8;
  for (int u = tid; u < TU; u += 256){
    int l = u / CU8, c = u % CU8;
    *(short8*)(ctx + (tokbase + (size_t)l*LST)*CC + g*CW + c*8) =
        *(const short8*)(SH + l*CW + c*8);
  }
}

// =======================================================================
extern "C" void kernel_launch(void* const* d_in, const int* in_sizes, int n_in,
                              void* d_out, int out_size, void* d_ws, size_t ws_size,
                              hipStream_t stream){
  const float* x      = (const float*)d_in[0];
  const float* wqkv1  = (const float*)d_in[1];
  const float* wout1  = (const float*)d_in[2];
  const float* wqkv2  = (const float*)d_in[3];
  const float* wout2  = (const float*)d_in[4];
  const float* g1 = (const float*)d_in[5];  const float* b1 = (const float*)d_in[6];
  const float* g2 = (const float*)d_in[7];  const float* b2 = (const float*)d_in[8];
  const float* g3 = (const float*)d_in[9];  const float* b3 = (const float*)d_in[10];
  const float* wfc1 = (const float*)d_in[11]; const float* bfc1 = (const float*)d_in[12];
  const float* wfc2 = (const float*)d_in[13]; const float* bfc2 = (const float*)d_in[14];

  // ---- workspace layout (461 MB total) ----
  char* ws = (char*)d_ws;
  size_t off = 0;
  auto alloc = [&](size_t bytes)->char*{
    char* p = ws + off; off += (bytes + 255) & ~(size_t)255; return p;
  };
  float* xres = (float*)alloc((size_t)NTOK*CC*4);            // 151.0 MB residual (f32)
  u16*   y    = (u16*)  alloc((size_t)NTOK*CC*2);            //  75.5 MB LN out / ctx
  u16*   qkv  = (u16*)  alloc((size_t)NTOK*1536*2);          // 226.5 MB q|k|v ; MLP h overlays
  u16* wqkv1p = (u16*)alloc((size_t)1536*512*2);
  u16* wqkv2p = (u16*)alloc((size_t)1536*512*2);
  u16* wout1p = (u16*)alloc((size_t)512*512*2);
  u16* wout2p = (u16*)alloc((size_t)512*512*2);
  u16* wfc1p  = (u16*)alloc((size_t)2048*512*2);
  u16* wfc2p  = (u16*)alloc((size_t)512*2048*2);
  u16*   hv   = qkv;                                         // MLP hidden half (151 MB <= 226.5 MB)

  // ---- d_out doubles as scratch (fully rewritten by k_tout at the end) ----
  u16*   P    = (u16*)d_out;
  u16*   vt   = (u16*)((char*)d_out + 28311552);
  float* S    = (float*)((char*)d_out + 28311552);
  (void)ws_size; (void)in_sizes; (void)n_in; (void)out_size;

  const float scale = 0.044194173824159216f;   // 1/sqrt(512)

  // weights
  k_permqkv<<<3072, 256, 0, stream>>>(wqkv1, wqkv1p);
  k_permqkv<<<3072, 256, 0, stream>>>(wqkv2, wqkv2p);
  k_conv<<<1024, 256, 0, stream>>>(wout1, wout1p, 512*512);
  k_conv<<<1024, 256, 0, stream>>>(wout2, wout2p, 512*512);
  k_conv<<<4096, 256, 0, stream>>>(wfc1, wfc1p, 2048*512);
  k_conv<<<4096, 256, 0, stream>>>(wfc2, wfc2p, 512*2048);

  // stage 0: layout
  k_tin<<<BB*HH*96, 256, 0, stream>>>(x, xres);

  // ---- attention 1 (along H; seq = (b,w), L=48) ----
  k_ln<<<NTOK/4, 256, 0, stream>>>(xres, g1, b1, y);
  k_gemm<<<576*12, 256, 0, stream>>>(y, 512, wqkv1p, 512, qkv, 1536, nullptr, 512, 12, 0);
  k_qk2<48,48,48,3><<<1536, 192, 0, stream>>>(qkv, qkv+512, 1536, S, 192, 9216, 1, 192, scale);
  k_softmax<<<NTOK/4, 256, 0, stream>>>(S, P, 48, 64);
  k_vt<<<1536*16, 256, 0, stream>>>(qkv+1024, 1536, vt, 48, 64, 192, 9216, 1, 192);
  k_pv2<48,64,3,16><<<1536*2, 256, 0, stream>>>(P, vt, y, 192, 9216, 1, 192);
  k_gemm<<<576*4, 256, 0, stream>>>(y, 512, wout1p, 512, xres, 512, nullptr, 512, 4, 2);

  // ---- attention 2 (along W; seq = (b,h), L=192) ----
  k_ln<<<NTOK/4, 256, 0, stream>>>(xres, g2, b2, y);
  k_gemm<<<576*12, 256, 0, stream>>>(y, 512, wqkv2p, 512, qkv, 1536, nullptr, 512, 12, 0);
  k_qk2<192,64,64,4><<<1152, 256, 0, stream>>>(qkv, qkv+512, 1536, S, 48, 9216, 192, 1, scale);
  k_softmax<<<NTOK/4, 256, 0, stream>>>(S, P, 192, 192);
  k_vt<<<384*16, 256, 0, stream>>>(qkv+1024, 1536, vt, 192, 192, 48, 9216, 192, 1);
  k_pv2<192,192,12,8><<<384*4, 256, 0, stream>>>(P, vt, y, 48, 9216, 192, 1);
  k_gemm<<<576*4, 256, 0, stream>>>(y, 512, wout2p, 512, xres, 512, nullptr, 512, 4, 2);

  // ---- MLP: two M-halves, each fc1 (full N=2048) then fc2 (single K=2048 pass) ----
  k_ln<<<NTOK/4, 256, 0, stream>>>(xres, g3, b3, y);
  for (int half = 0; half < 2; half++){
    size_t M0 = (size_t)half * 36864;
    k_gemm<<<288*16, 256, 0, stream>>>(y + M0*512, 512, wfc1p, 512, hv, 2048, bfc1, 512, 16, 1);
    k_gemm<<<288*4, 256, 0, stream>>>(hv, 2048, wfc2p, 2048, xres + M0*512, 512, bfc2, 2048, 4, 2);
  }

  // output layout
  k_tout<<<BB*HH*96, 256, 0, stream>>>(xres, (float*)d_out);
}